// Round 13
// baseline (178.111 us; speedup 1.0000x reference)
//
#include <hip/hip_runtime.h>
#include <hip/hip_bf16.h>
#include <cstdint>

// Problem constants
#define CIN   256
#define COUT  256
#define NB    8
#define NT    16
#define NH    28
#define NW    28
#define HP    30
#define WP    30

#define XM_ELEMS   ((size_t)NB * NT * HP * WP * CIN)   // 29,491,200 bf16
#define XM_BYTES   (XM_ELEMS * 2)

typedef __bf16 bf16x8 __attribute__((ext_vector_type(8)));
typedef float  f32x4  __attribute__((ext_vector_type(4)));

#define AS1 __attribute__((address_space(1)))
#define AS3 __attribute__((address_space(3)))

static __device__ __forceinline__ unsigned short f2bf(float f) {
    __hip_bfloat16 h = __float2bfloat16(f);
    return __builtin_bit_cast(unsigned short, h);
}

// ---------------------------------------------------------------------------
// Pass 1: xm[b][t][hp][wp][ci] = bf16(x[b][ci][t][h][w] * alpha[b][ci][t])
// ---------------------------------------------------------------------------
__global__ void modulate_kernel(const float* __restrict__ x,
                                const float* __restrict__ alpha,
                                unsigned short* __restrict__ xm) {
    const int ci = threadIdx.x;
    const int blk = blockIdx.x;
    const int hp = blk % 30;
    const int bt = blk / 30;
    unsigned short* row = xm + (size_t)(bt * 900 + hp * 30) * 256;
    if (hp == 0 || hp == 29) {
        #pragma unroll
        for (int wp = 0; wp < 30; ++wp) row[wp * 256 + ci] = 0;
        return;
    }
    const int t = bt & 15, b = bt >> 4;
    const int h = hp - 1;
    const float a = alpha[(b * CIN + ci) * NT + t];
    const float* xrow = x + ((size_t)((b * CIN + ci) * NT + t) * NH + h) * NW;
    row[ci] = 0;
    row[29 * 256 + ci] = 0;
    const float4* xv = (const float4*)xrow;
    #pragma unroll
    for (int q = 0; q < 7; ++q) {
        float4 v = xv[q];
        row[(q * 4 + 1) * 256 + ci] = f2bf(v.x * a);
        row[(q * 4 + 2) * 256 + ci] = f2bf(v.y * a);
        row[(q * 4 + 3) * 256 + ci] = f2bf(v.z * a);
        row[(q * 4 + 4) * 256 + ci] = f2bf(v.w * a);
    }
}

// ---------------------------------------------------------------------------
// Pass 2: wB[tap][co][ci] = bf16(weight[co][ci][tap])
// ---------------------------------------------------------------------------
__global__ void repack_w_kernel(const float* __restrict__ w,
                                unsigned short* __restrict__ wB) {
    const int ci = threadIdx.x;
    const int tap = blockIdx.x >> 8;
    const int co  = blockIdx.x & 255;
    wB[((tap * 256 + co) * 256) + ci] = f2bf(w[(co * 256 + ci) * 9 + tap]);
}

// ---------------------------------------------------------------------------
// Pass 3: 256(co) x 112(n) implicit GEMM, BK=32, 72 kt, TAP-INNER.
// R13: R10's exact 3-deep counted-vmcnt reg-dbuf schedule, but blocks of
// 4 waves (4M x 1N, wave 64co x 112n) with BN=112, grid 896 -> TWO
// independent blocks (barrier groups) per CU. Same per-CU LDS/MFMA
// intensity as R10; independent groups can anti-phase (one group's
// ds_read phase under the other's MFMA phase) -- the overlap a single
// lockstep 8-wave group cannot achieve. LDS 72KB = 3 x (A 16KB + B 8KB);
// 2 blocks/CU = 144KB. 6 loads/wave/stage; body VMW(6) = 2-body lead;
// never vmcnt(0) in main loop. 64B rows, swizzle slot ^= (row>>1)&3
// (0-conflict verified), pre-swizzled global_load_lds source.
// ---------------------------------------------------------------------------

#define BAR()    __builtin_amdgcn_s_barrier()
#define LGKM0()  asm volatile("s_waitcnt lgkmcnt(0)" ::: "memory")
#define VMW(N)   asm volatile("s_waitcnt vmcnt(" #N ")" ::: "memory")
#define SCHED0() __builtin_amdgcn_sched_barrier(0)
#define PRIO(x)  __builtin_amdgcn_s_setprio(x)

// stage K-tile (tapS,cicS) into buf P (0..2): A 256x32 (4 loads/wave),
// B 112(+dup to 128)x32 (2 loads/wave). Advances tapS/cicS.
#define STAGE_F(P) do {                                                       \
    const int kh2 = (tapS * 11) >> 5;                                         \
    const int kw2 = tapS - 3 * kh2;                                           \
    const int aOff = tapS * 65536 + cicS * 32;                                \
    const int bOff = ((kh2 - 1) * 30 + (kw2 - 1)) * 256 + cicS * 32;          \
    _Pragma("unroll") for (int c_ = 0; c_ < 4; ++c_)                          \
        __builtin_amdgcn_global_load_lds(                                     \
            (const AS1 void*)(aSrc + aOff + c_ * 16384),                      \
            (AS3 void*)(lds + (P)*24576 + (c_*64 + wv*16)*64 + lane*16),      \
            16, 0, 0);                                                        \
    _Pragma("unroll") for (int c_ = 0; c_ < 2; ++c_)                          \
        __builtin_amdgcn_global_load_lds(                                     \
            (const AS1 void*)(bL[c_] + bOff),                                 \
            (AS3 void*)(lds + (P)*24576 + 16384 + (c_*64 + wv*16)*64 + lane*16), \
            16, 0, 0);                                                        \
    if (++tapS == 9) { tapS = 0; ++cicS; }                                    \
} while (0)

#define READF(S, P) do {                                                      \
    _Pragma("unroll") for (int m_ = 0; m_ < 4; ++m_)                          \
        fa##S[m_] = *(const bf16x8*)(lds + (P)*24576 +                        \
            (wv*64 + m_*16 + l15)*64 + readSwz);                              \
    _Pragma("unroll") for (int f_ = 0; f_ < 7; ++f_)                          \
        fb##S[f_] = *(const bf16x8*)(lds + (P)*24576 + 16384 +                \
            (f_*16 + l15)*64 + readSwz);                                      \
} while (0)

#define MFMA28(S) do {                                                        \
    _Pragma("unroll") for (int m_ = 0; m_ < 4; ++m_)                          \
    _Pragma("unroll") for (int f_ = 0; f_ < 7; ++f_)                          \
        acc[m_][f_] = __builtin_amdgcn_mfma_f32_16x16x32_bf16(                \
            fb##S[f_], fa##S[m_], acc[m_][f_], 0, 0, 0);                      \
} while (0)

// body j: compute CS=frags(j); read frags(j+1)->NS from NBUF=(j+1)%3;
// stage S(j+3) -> SBUF=j%3. VMW(6) drains S(j+1) (issued 2 bodies ago).
#define BODY_S(CS, NS, NBUF, SBUF) do {                                       \
    VMW(6);                                                                   \
    SCHED0();                                                                 \
    BAR();                                                                    \
    READF(NS, NBUF);                                                          \
    STAGE_F(SBUF);                                                            \
    SCHED0();                                                                 \
    PRIO(1); MFMA28(CS); PRIO(0);                                             \
    LGKM0();                                                                  \
    SCHED0();                                                                 \
} while (0)

// tail body (no stage); VMN = counted vmcnt target
#define BODY_N(CS, NS, NBUF, VMN) do {                                        \
    VMW(VMN);                                                                 \
    SCHED0();                                                                 \
    BAR();                                                                    \
    READF(NS, NBUF);                                                          \
    SCHED0();                                                                 \
    PRIO(1); MFMA28(CS); PRIO(0);                                             \
    LGKM0();                                                                  \
    SCHED0();                                                                 \
} while (0)

__global__ __launch_bounds__(256, 2) void conv_gemm_kernel(
    const unsigned short* __restrict__ xm,
    const unsigned short* __restrict__ wB,
    float* __restrict__ out) {
    __shared__ __align__(1024) char lds[73728];   // 3 x (A 16KB + B 8KB)

    const int tid  = threadIdx.x;
    const int wv   = tid >> 6;             // 0..3: co quarter (wm = wv)
    const int lane = tid & 63;
    const int l15  = lane & 15;
    const int n0   = blockIdx.x * 112;

    // ---- staging sources (pre-swizzled ci slot; inverse of read swizzle) ----
    const int swzE = 8 * ((lane & 3) ^ ((lane >> 3) & 3));
    const unsigned short* aSrc = wB + (wv * 16 + (lane >> 2)) * 256 + swzE;

    const unsigned short* bL[2];
    #pragma unroll
    for (int c_ = 0; c_ < 2; ++c_) {
        int nl = c_ * 64 + wv * 16 + (lane >> 2);      // 0..127
        nl = nl > 111 ? 111 : nl;                      // pad rows duplicate
        const int n  = n0 + nl;
        const int w_ = n % 28, h_ = (n / 28) % 28, bt = n / 784;
        bL[c_] = xm + (size_t)((bt * 30 + h_ + 1) * 30 + (w_ + 1)) * 256 + swzE;
    }

    // ---- fragment read base (slot swizzle (row>>1)&3, verified) ----
    const int readSwz = ((lane >> 4) ^ ((l15 >> 1) & 3)) << 4;

    f32x4 acc[4][7];
    #pragma unroll
    for (int i = 0; i < 4; ++i)
        #pragma unroll
        for (int j = 0; j < 7; ++j) acc[i][j] = f32x4{0.f, 0.f, 0.f, 0.f};

    bf16x8 faA[4], fbA[7], faB[4], fbB[7];

    int tapS = 0, cicS = 0;
    // ---- prologue: S(0)->b0, S(1)->b1, S(2)->b2; frags(0) -> set A ----
    STAGE_F(0);
    STAGE_F(1);
    STAGE_F(2);
    VMW(12);                       // my S(0) landed (S(1),S(2) in flight)
    SCHED0();
    BAR();                         // all waves' S(0) landed
    READF(A, 0);                   // frags(0)
    LGKM0();
    SCHED0();

    // main: bodies j=0..65, pattern period 6 (buf%3 x set%2)
    #pragma unroll 1
    for (int it = 0; it < 11; ++it) {
        BODY_S(A, B, 1, 0);        // j=6it+0
        BODY_S(B, A, 2, 1);        // j=6it+1
        BODY_S(A, B, 0, 2);        // j=6it+2
        BODY_S(B, A, 1, 0);        // j=6it+3
        BODY_S(A, B, 2, 1);        // j=6it+4
        BODY_S(B, A, 0, 2);        // j=6it+5
    }
    // tail: j=66..70 (stages S(69..71) at j=66..68), then peel j=71
    BODY_S(A, B, 1, 0);            // j=66: stage S(69)
    BODY_S(B, A, 2, 1);            // j=67: stage S(70)
    BODY_S(A, B, 0, 2);            // j=68: stage S(71)
    BODY_N(B, A, 1, 6);            // j=69: drain S(70)
    BODY_N(A, B, 2, 0);            // j=70: drain S(71), read frags(71)
    PRIO(1); MFMA28(B); PRIO(0);   // j=71

    // ---- C-write: lane holds 4 consecutive n (rows) at one co (col) ----
    #pragma unroll
    for (int f = 0; f < 7; ++f) {
        const int n  = n0 + f * 16 + ((lane >> 4) << 2);
        const int bt = n / 784;
        const int hw = n - bt * 784;
        const int b = bt >> 4, t = bt & 15;
        float* obase = out + ((size_t)(b * 256) * 16 + t) * 784 + hw;
        #pragma unroll
        for (int m = 0; m < 4; ++m) {
            const int co = wv * 64 + m * 16 + l15;
            *(f32x4*)(obase + (size_t)co * 12544) = acc[m][f];
        }
    }
}

// ---------------------------------------------------------------------------
extern "C" void kernel_launch(void* const* d_in, const int* in_sizes, int n_in,
                              void* d_out, int out_size, void* d_ws, size_t ws_size,
                              hipStream_t stream) {
    const float* x      = (const float*)d_in[0];
    const float* alpha  = (const float*)d_in[1];
    const float* weight = (const float*)d_in[2];
    float* out = (float*)d_out;

    unsigned short* xm = (unsigned short*)d_ws;
    unsigned short* wB = (unsigned short*)((char*)d_ws + XM_BYTES);

    modulate_kernel<<<dim3(NB * NT * HP), dim3(256), 0, stream>>>(x, alpha, xm);
    repack_w_kernel<<<dim3(9 * 256), dim3(256), 0, stream>>>(weight, wB);
    conv_gemm_kernel<<<dim3(896), dim3(256), 0, stream>>>(xm, wB, out);
}

// Round 14
// 169.269 us; speedup vs baseline: 1.0522x; 1.0522x over previous
//
#include <hip/hip_runtime.h>
#include <hip/hip_bf16.h>
#include <cstdint>

// Problem constants
#define CIN   256
#define COUT  256
#define NB    8
#define NT    16
#define NH    28
#define NW    28
#define HP    30
#define WP    30

#define XM_ELEMS   ((size_t)NB * NT * HP * WP * CIN)   // 29,491,200 bf16
#define XM_BYTES   (XM_ELEMS * 2)

typedef __bf16 bf16x8 __attribute__((ext_vector_type(8)));
typedef float  f32x4  __attribute__((ext_vector_type(4)));

#define AS1 __attribute__((address_space(1)))
#define AS3 __attribute__((address_space(3)))

static __device__ __forceinline__ unsigned short f2bf(float f) {
    __hip_bfloat16 h = __float2bfloat16(f);
    return __builtin_bit_cast(unsigned short, h);
}

// ---------------------------------------------------------------------------
// Pass 1: xm[b][t][hp][wp][ci] = bf16(x[b][ci][t][h][w] * alpha[b][ci][t])
// ---------------------------------------------------------------------------
__global__ void modulate_kernel(const float* __restrict__ x,
                                const float* __restrict__ alpha,
                                unsigned short* __restrict__ xm) {
    const int ci = threadIdx.x;
    const int blk = blockIdx.x;
    const int hp = blk % 30;
    const int bt = blk / 30;
    unsigned short* row = xm + (size_t)(bt * 900 + hp * 30) * 256;
    if (hp == 0 || hp == 29) {
        #pragma unroll
        for (int wp = 0; wp < 30; ++wp) row[wp * 256 + ci] = 0;
        return;
    }
    const int t = bt & 15, b = bt >> 4;
    const int h = hp - 1;
    const float a = alpha[(b * CIN + ci) * NT + t];
    const float* xrow = x + ((size_t)((b * CIN + ci) * NT + t) * NH + h) * NW;
    row[ci] = 0;
    row[29 * 256 + ci] = 0;
    const float4* xv = (const float4*)xrow;
    #pragma unroll
    for (int q = 0; q < 7; ++q) {
        float4 v = xv[q];
        row[(q * 4 + 1) * 256 + ci] = f2bf(v.x * a);
        row[(q * 4 + 2) * 256 + ci] = f2bf(v.y * a);
        row[(q * 4 + 3) * 256 + ci] = f2bf(v.z * a);
        row[(q * 4 + 4) * 256 + ci] = f2bf(v.w * a);
    }
}

// ---------------------------------------------------------------------------
// Pass 2: wB[tap][co][ci] = bf16(weight[co][ci][tap])
// ---------------------------------------------------------------------------
__global__ void repack_w_kernel(const float* __restrict__ w,
                                unsigned short* __restrict__ wB) {
    const int ci = threadIdx.x;
    const int tap = blockIdx.x >> 8;
    const int co  = blockIdx.x & 255;
    wB[((tap * 256 + co) * 256) + ci] = f2bf(w[(co * 256 + ci) * 9 + tap]);
}

// ---------------------------------------------------------------------------
// Pass 3: 256(co) x 224(n) implicit GEMM, BK=32, 72 kt, TAP-INNER (L2-hot).
// R14: ONE WAVE PER SIMD. Block = 4 waves (2M x 2N), wave tile 128co x
// 112n (acc 8x7 = 224 regs), __launch_bounds__(256,1) -> ~512-reg budget.
// A single wave per SIMD self-overlaps: it issues the next kt's 15
// ds_read_b128 + 8 stage-loads, then 56 MFMAs occupy the matrix pipe
// (~1086 cy/SIMD) while the LDS port drains reads+writes (~740 cy)
// underneath -- no sibling wave to convoy with (the R10-R13 limiter).
// FLOP per LDS byte +47% vs 64x112 waves. R10's 3-deep staging + counted
// vmcnt kept: body VMW(8) drains S(j+1) issued 2 bodies (~2500cy) ago;
// never vmcnt(0) in main loop. LDS 96KB = 3 x (A 16KB + B 16KB). 64B
// rows, swizzle slot ^= (row>>1)&3 (0-conflict verified), pre-swizzled
// global_load_lds source. grid = 448, block = 256.
// ---------------------------------------------------------------------------

#define BAR()    __builtin_amdgcn_s_barrier()
#define LGKM0()  asm volatile("s_waitcnt lgkmcnt(0)" ::: "memory")
#define VMW(N)   asm volatile("s_waitcnt vmcnt(" #N ")" ::: "memory")
#define SCHED0() __builtin_amdgcn_sched_barrier(0)

// stage K-tile (tapS,cicS) into buf P (0..2): A 256x32 (4 loads/wave) +
// B 224(+dup)x32 (4 loads/wave). Advances tapS/cicS.
#define STAGE_F(P) do {                                                       \
    const int kh2 = (tapS * 11) >> 5;                                         \
    const int kw2 = tapS - 3 * kh2;                                           \
    const int aOff = tapS * 65536 + cicS * 32;                                \
    const int bOff = ((kh2 - 1) * 30 + (kw2 - 1)) * 256 + cicS * 32;          \
    _Pragma("unroll") for (int c_ = 0; c_ < 4; ++c_)                          \
        __builtin_amdgcn_global_load_lds(                                     \
            (const AS1 void*)(aSrc + aOff + c_ * 16384),                      \
            (AS3 void*)(lds + (P)*32768 + (c_*64 + wv*16)*64 + lane*16),      \
            16, 0, 0);                                                        \
    _Pragma("unroll") for (int c_ = 0; c_ < 4; ++c_)                          \
        __builtin_amdgcn_global_load_lds(                                     \
            (const AS1 void*)(bL[c_] + bOff),                                 \
            (AS3 void*)(lds + (P)*32768 + 16384 + (c_*64 + wv*16)*64 + lane*16), \
            16, 0, 0);                                                        \
    if (++tapS == 9) { tapS = 0; ++cicS; }                                    \
} while (0)

#define READF(S, P) do {                                                      \
    _Pragma("unroll") for (int m_ = 0; m_ < 8; ++m_)                          \
        fa##S[m_] = *(const bf16x8*)(lds + (P)*32768 +                        \
            (wm*128 + m_*16 + l15)*64 + readSwz);                             \
    _Pragma("unroll") for (int f_ = 0; f_ < 7; ++f_)                          \
        fb##S[f_] = *(const bf16x8*)(lds + (P)*32768 + 16384 +                \
            (wn*112 + f_*16 + l15)*64 + readSwz);                             \
} while (0)

#define MFMA56(S) do {                                                        \
    _Pragma("unroll") for (int m_ = 0; m_ < 8; ++m_)                          \
    _Pragma("unroll") for (int f_ = 0; f_ < 7; ++f_)                          \
        acc[m_][f_] = __builtin_amdgcn_mfma_f32_16x16x32_bf16(                \
            fb##S[f_], fa##S[m_], acc[m_][f_], 0, 0, 0);                      \
} while (0)

// body j: compute CS=frags(j); read frags(j+1)->NS from NBUF=(j+1)%3;
// stage S(j+3) -> SBUF=j%3. VMW(8) drains S(j+1) (issued 2 bodies ago).
#define BODY_S(CS, NS, NBUF, SBUF) do {                                       \
    VMW(8);                                                                   \
    SCHED0();                                                                 \
    BAR();                                                                    \
    READF(NS, NBUF);                                                          \
    STAGE_F(SBUF);                                                            \
    SCHED0();                                                                 \
    MFMA56(CS);                                                               \
    LGKM0();                                                                  \
    SCHED0();                                                                 \
} while (0)

// tail body (no stage); VMN = counted vmcnt target
#define BODY_N(CS, NS, NBUF, VMN) do {                                        \
    VMW(VMN);                                                                 \
    SCHED0();                                                                 \
    BAR();                                                                    \
    READF(NS, NBUF);                                                          \
    SCHED0();                                                                 \
    MFMA56(CS);                                                               \
    LGKM0();                                                                  \
    SCHED0();                                                                 \
} while (0)

__global__ __launch_bounds__(256, 1) void conv_gemm_kernel(
    const unsigned short* __restrict__ xm,
    const unsigned short* __restrict__ wB,
    float* __restrict__ out) {
    __shared__ __align__(1024) char lds[98304];   // 3 x (A 16KB + B 16KB)

    const int tid  = threadIdx.x;
    const int wv   = tid >> 6;             // 0..3
    const int lane = tid & 63;
    const int l15  = lane & 15;
    const int n0   = blockIdx.x * 224;
    const int wm   = wv >> 1;              // 0..1: co half (128)
    const int wn   = wv & 1;               // 0..1: n half (112)

    // ---- staging sources (pre-swizzled ci slot; inverse of read swizzle) ----
    const int swzE = 8 * ((lane & 3) ^ ((lane >> 3) & 3));
    const unsigned short* aSrc = wB + (wv * 16 + (lane >> 2)) * 256 + swzE;

    const unsigned short* bL[4];
    #pragma unroll
    for (int c_ = 0; c_ < 4; ++c_) {
        int nl = c_ * 64 + wv * 16 + (lane >> 2);      // 0..255
        nl = nl > 223 ? 223 : nl;                      // pad rows duplicate
        const int n  = n0 + nl;
        const int w_ = n % 28, h_ = (n / 28) % 28, bt = n / 784;
        bL[c_] = xm + (size_t)((bt * 30 + h_ + 1) * 30 + (w_ + 1)) * 256 + swzE;
    }

    // ---- fragment read base (slot swizzle (row>>1)&3, verified) ----
    const int readSwz = ((lane >> 4) ^ ((l15 >> 1) & 3)) << 4;

    f32x4 acc[8][7];
    #pragma unroll
    for (int i = 0; i < 8; ++i)
        #pragma unroll
        for (int j = 0; j < 7; ++j) acc[i][j] = f32x4{0.f, 0.f, 0.f, 0.f};

    bf16x8 faA[8], fbA[7], faB[8], fbB[7];

    int tapS = 0, cicS = 0;
    // ---- prologue: S(0)->b0, S(1)->b1, S(2)->b2; frags(0) -> set A ----
    STAGE_F(0);
    STAGE_F(1);
    STAGE_F(2);
    VMW(16);                       // my S(0) landed (S(1),S(2) in flight)
    SCHED0();
    BAR();                         // all waves' S(0) landed
    READF(A, 0);                   // frags(0)
    LGKM0();
    SCHED0();

    // main: bodies j=0..65, pattern period 6 (buf%3 x set%2)
    #pragma unroll 1
    for (int it = 0; it < 11; ++it) {
        BODY_S(A, B, 1, 0);        // j=6it+0
        BODY_S(B, A, 2, 1);        // j=6it+1
        BODY_S(A, B, 0, 2);        // j=6it+2
        BODY_S(B, A, 1, 0);        // j=6it+3
        BODY_S(A, B, 2, 1);        // j=6it+4
        BODY_S(B, A, 0, 2);        // j=6it+5
    }
    // tail: j=66..70 (stages S(69..71) at j=66..68), then peel j=71
    BODY_S(A, B, 1, 0);            // j=66: stage S(69)
    BODY_S(B, A, 2, 1);            // j=67: stage S(70)
    BODY_S(A, B, 0, 2);            // j=68: stage S(71)
    BODY_N(B, A, 1, 8);            // j=69: drain S(70)
    BODY_N(A, B, 2, 0);            // j=70: drain S(71), read frags(71)
    MFMA56(B);                     // j=71

    // ---- C-write: lane holds 4 consecutive n (rows) at one co (col) ----
    #pragma unroll
    for (int f = 0; f < 7; ++f) {
        const int n  = n0 + wn * 112 + f * 16 + ((lane >> 4) << 2);
        const int bt = n / 784;
        const int hw = n - bt * 784;
        const int b = bt >> 4, t = bt & 15;
        float* obase = out + ((size_t)(b * 256) * 16 + t) * 784 + hw;
        #pragma unroll
        for (int m = 0; m < 8; ++m) {
            const int co = wm * 128 + m * 16 + l15;
            *(f32x4*)(obase + (size_t)co * 12544) = acc[m][f];
        }
    }
}

// ---------------------------------------------------------------------------
extern "C" void kernel_launch(void* const* d_in, const int* in_sizes, int n_in,
                              void* d_out, int out_size, void* d_ws, size_t ws_size,
                              hipStream_t stream) {
    const float* x      = (const float*)d_in[0];
    const float* alpha  = (const float*)d_in[1];
    const float* weight = (const float*)d_in[2];
    float* out = (float*)d_out;

    unsigned short* xm = (unsigned short*)d_ws;
    unsigned short* wB = (unsigned short*)((char*)d_ws + XM_BYTES);

    modulate_kernel<<<dim3(NB * NT * HP), dim3(256), 0, stream>>>(x, alpha, xm);
    repack_w_kernel<<<dim3(9 * 256), dim3(256), 0, stream>>>(weight, wB);
    conv_gemm_kernel<<<dim3(448), dim3(256), 0, stream>>>(xm, wB, out);
}

// Round 15
// 156.807 us; speedup vs baseline: 1.1359x; 1.0795x over previous
//
#include <hip/hip_runtime.h>
#include <hip/hip_bf16.h>
#include <cstdint>

// Problem constants
#define CIN   256
#define COUT  256
#define NB    8
#define NT    16
#define NH    28
#define NW    28
#define HP    30
#define WP    30

#define XM_ELEMS   ((size_t)NB * NT * HP * WP * CIN)   // 29,491,200 bf16
#define XM_BYTES   (XM_ELEMS * 2)

typedef __bf16 bf16x8 __attribute__((ext_vector_type(8)));
typedef float  f32x4  __attribute__((ext_vector_type(4)));

#define AS1 __attribute__((address_space(1)))
#define AS3 __attribute__((address_space(3)))

static __device__ __forceinline__ unsigned short f2bf(float f) {
    __hip_bfloat16 h = __float2bfloat16(f);
    return __builtin_bit_cast(unsigned short, h);
}

// ---------------------------------------------------------------------------
// Pass 1: xm[b][t][hp][wp][ci] = bf16(x[b][ci][t][h][w] * alpha[b][ci][t])
// ---------------------------------------------------------------------------
__global__ void modulate_kernel(const float* __restrict__ x,
                                const float* __restrict__ alpha,
                                unsigned short* __restrict__ xm) {
    const int ci = threadIdx.x;
    const int blk = blockIdx.x;
    const int hp = blk % 30;
    const int bt = blk / 30;
    unsigned short* row = xm + (size_t)(bt * 900 + hp * 30) * 256;
    if (hp == 0 || hp == 29) {
        #pragma unroll
        for (int wp = 0; wp < 30; ++wp) row[wp * 256 + ci] = 0;
        return;
    }
    const int t = bt & 15, b = bt >> 4;
    const int h = hp - 1;
    const float a = alpha[(b * CIN + ci) * NT + t];
    const float* xrow = x + ((size_t)((b * CIN + ci) * NT + t) * NH + h) * NW;
    row[ci] = 0;
    row[29 * 256 + ci] = 0;
    const float4* xv = (const float4*)xrow;
    #pragma unroll
    for (int q = 0; q < 7; ++q) {
        float4 v = xv[q];
        row[(q * 4 + 1) * 256 + ci] = f2bf(v.x * a);
        row[(q * 4 + 2) * 256 + ci] = f2bf(v.y * a);
        row[(q * 4 + 3) * 256 + ci] = f2bf(v.z * a);
        row[(q * 4 + 4) * 256 + ci] = f2bf(v.w * a);
    }
}

// ---------------------------------------------------------------------------
// Pass 2: wB[tap][co][ci] = bf16(weight[co][ci][tap])
// ---------------------------------------------------------------------------
__global__ void repack_w_kernel(const float* __restrict__ w,
                                unsigned short* __restrict__ wB) {
    const int ci = threadIdx.x;
    const int tap = blockIdx.x >> 8;
    const int co  = blockIdx.x & 255;
    wB[((tap * 256 + co) * 256) + ci] = f2bf(w[(co * 256 + ci) * 9 + tap]);
}

// ---------------------------------------------------------------------------
// Pass 3: R10's exact 3-deep counted-vmcnt schedule, MIXED-BN grid for
// packing: 64 blocks of BN=224 (NF=7 frags/wave) + 448 blocks of BN=192
// (NF=6) = 512 blocks covering N=100352 exactly. Greedy CU packing gives
// makespan 1.875xT_big vs 2.0xT_big for 448 equal blocks (-6.3%); worst
// case identical to R10. Template<NF> body, both paths fully unrolled,
// block-uniform branch. 256(co) x BN implicit GEMM, BK=32, 72 kt,
// TAP-INNER (L2-hot, FETCH~45MB). 8 waves 4Mx2N, wave 64co x NF*16 n,
// acc 4xNF. LDS 96KB = 3 x (A 16KB + B 16KB); body VMW(4) drains S(j+1)
// issued 2 bodies (~4000cy) ago; never vmcnt(0) in main loop. 64B rows,
// swizzle slot ^= (row>>1)&3 (0-conflict verified), pre-swizzled
// global_load_lds source.
// ---------------------------------------------------------------------------

#define BAR()    __builtin_amdgcn_s_barrier()
#define LGKM0()  asm volatile("s_waitcnt lgkmcnt(0)" ::: "memory")
#define VMW(N)   asm volatile("s_waitcnt vmcnt(" #N ")" ::: "memory")
#define SCHED0() __builtin_amdgcn_sched_barrier(0)
#define PRIO(x)  __builtin_amdgcn_s_setprio(x)

// stage K-tile (tapS,cicS) into buf P (0..2): A 256x32 (2 loads/wave),
// B 256(BN+dup)x32 (2 loads/wave). Advances tapS/cicS.
#define STAGE_F(P) do {                                                       \
    const int kh2 = (tapS * 11) >> 5;                                         \
    const int kw2 = tapS - 3 * kh2;                                           \
    const int aOff = tapS * 65536 + cicS * 32;                                \
    const int bOff = ((kh2 - 1) * 30 + (kw2 - 1)) * 256 + cicS * 32;          \
    _Pragma("unroll") for (int c_ = 0; c_ < 2; ++c_)                          \
        __builtin_amdgcn_global_load_lds(                                     \
            (const AS1 void*)(aSrc + aOff + c_ * 32768),                      \
            (AS3 void*)(lds + (P)*32768 + (c_*128 + wave*16)*64 + lane*16),   \
            16, 0, 0);                                                        \
    _Pragma("unroll") for (int c_ = 0; c_ < 2; ++c_)                          \
        __builtin_amdgcn_global_load_lds(                                     \
            (const AS1 void*)(bL[c_] + bOff),                                 \
            (AS3 void*)(lds + (P)*32768 + 16384 + (c_*128 + wave*16)*64 + lane*16), \
            16, 0, 0);                                                        \
    if (++tapS == 9) { tapS = 0; ++cicS; }                                    \
} while (0)

#define READF(S, P) do {                                                      \
    _Pragma("unroll") for (int m_ = 0; m_ < 4; ++m_)                          \
        fa##S[m_] = *(const bf16x8*)(lds + (P)*32768 +                        \
            (wm*64 + m_*16 + l15)*64 + readSwz);                              \
    _Pragma("unroll") for (int f_ = 0; f_ < NF; ++f_)                         \
        fb##S[f_] = *(const bf16x8*)(lds + (P)*32768 + 16384 +                \
            (wn*(NF*16) + f_*16 + l15)*64 + readSwz);                         \
} while (0)

#define MFMA_T(S) do {                                                        \
    _Pragma("unroll") for (int m_ = 0; m_ < 4; ++m_)                          \
    _Pragma("unroll") for (int f_ = 0; f_ < NF; ++f_)                         \
        acc[m_][f_] = __builtin_amdgcn_mfma_f32_16x16x32_bf16(                \
            fb##S[f_], fa##S[m_], acc[m_][f_], 0, 0, 0);                      \
} while (0)

// body j: compute CS=frags(j); read frags(j+1)->NS from NBUF=(j+1)%3;
// stage S(j+3) -> SBUF=j%3. VMW(4) drains S(j+1) (issued 2 bodies ago).
#define BODY_S(CS, NS, NBUF, SBUF) do {                                       \
    VMW(4);                                                                   \
    SCHED0();                                                                 \
    BAR();                                                                    \
    READF(NS, NBUF);                                                          \
    STAGE_F(SBUF);                                                            \
    SCHED0();                                                                 \
    PRIO(1); MFMA_T(CS); PRIO(0);                                             \
    LGKM0();                                                                  \
    SCHED0();                                                                 \
} while (0)

// tail body (no stage); VMN = counted vmcnt target
#define BODY_N(CS, NS, NBUF, VMN) do {                                        \
    VMW(VMN);                                                                 \
    SCHED0();                                                                 \
    BAR();                                                                    \
    READF(NS, NBUF);                                                          \
    SCHED0();                                                                 \
    PRIO(1); MFMA_T(CS); PRIO(0);                                             \
    LGKM0();                                                                  \
    SCHED0();                                                                 \
} while (0)

template<int NF>
__device__ __forceinline__ void conv_body(
    const unsigned short* __restrict__ xm,
    const unsigned short* __restrict__ wB,
    float* __restrict__ out,
    char* lds, const int n0)
{
    const int tid  = threadIdx.x;
    const int wave = tid >> 6;             // 0..7
    const int lane = tid & 63;
    const int l15  = lane & 15;
    const int wm   = wave >> 1;            // 0..3 co quarter (64)
    const int wn   = wave & 1;             // 0..1 n half (NF*16)
    const int BN   = NF * 32;              // 224 or 192

    // ---- staging sources (pre-swizzled ci slot; inverse of read swizzle) ----
    const int swzE = 8 * ((lane & 3) ^ ((lane >> 3) & 3));
    const unsigned short* aSrc = wB + (wave * 16 + (lane >> 2)) * 256 + swzE;

    const unsigned short* bL[2];
    #pragma unroll
    for (int c_ = 0; c_ < 2; ++c_) {
        int nl = c_ * 128 + wave * 16 + (lane >> 2);   // 0..255
        nl = nl > BN - 1 ? BN - 1 : nl;                // pad rows duplicate
        const int n  = n0 + nl;
        const int w_ = n % 28, h_ = (n / 28) % 28, bt = n / 784;
        bL[c_] = xm + (size_t)((bt * 30 + h_ + 1) * 30 + (w_ + 1)) * 256 + swzE;
    }

    // ---- fragment read base (slot swizzle (row>>1)&3, verified) ----
    const int readSwz = ((lane >> 4) ^ ((l15 >> 1) & 3)) << 4;

    f32x4 acc[4][NF];
    #pragma unroll
    for (int i = 0; i < 4; ++i)
        #pragma unroll
        for (int j = 0; j < NF; ++j) acc[i][j] = f32x4{0.f, 0.f, 0.f, 0.f};

    bf16x8 faA[4], fbA[NF], faB[4], fbB[NF];

    int tapS = 0, cicS = 0;
    // ---- prologue: S(0)->b0, S(1)->b1, S(2)->b2; frags(0) -> set A ----
    STAGE_F(0);
    STAGE_F(1);
    STAGE_F(2);
    VMW(8);                        // my S(0) landed (S(1),S(2) in flight)
    SCHED0();
    BAR();                         // all waves' S(0) landed
    READF(A, 0);                   // frags(0)
    LGKM0();
    SCHED0();

    // main: bodies j=0..65, pattern period 6 (buf%3 x set%2)
    #pragma unroll 1
    for (int it = 0; it < 11; ++it) {
        BODY_S(A, B, 1, 0);        // j=6it+0
        BODY_S(B, A, 2, 1);        // j=6it+1
        BODY_S(A, B, 0, 2);        // j=6it+2
        BODY_S(B, A, 1, 0);        // j=6it+3
        BODY_S(A, B, 2, 1);        // j=6it+4
        BODY_S(B, A, 0, 2);        // j=6it+5
    }
    // tail: j=66..70 (stages S(69..71) at j=66..68), then peel j=71
    BODY_S(A, B, 1, 0);            // j=66: stage S(69)
    BODY_S(B, A, 2, 1);            // j=67: stage S(70)
    BODY_S(A, B, 0, 2);            // j=68: stage S(71)
    BODY_N(B, A, 1, 4);            // j=69: drain S(70)
    BODY_N(A, B, 2, 0);            // j=70: drain S(71), read frags(71)
    PRIO(1); MFMA_T(B); PRIO(0);   // j=71

    // ---- C-write: lane holds 4 consecutive n (rows) at one co (col) ----
    #pragma unroll
    for (int f = 0; f < NF; ++f) {
        const int n  = n0 + wn * (NF * 16) + f * 16 + ((lane >> 4) << 2);
        const int bt = n / 784;
        const int hw = n - bt * 784;
        const int b = bt >> 4, t = bt & 15;
        float* obase = out + ((size_t)(b * 256) * 16 + t) * 784 + hw;
        #pragma unroll
        for (int m = 0; m < 4; ++m) {
            const int co = wm * 64 + m * 16 + l15;
            *(f32x4*)(obase + (size_t)co * 12544) = acc[m][f];
        }
    }
}

// Mixed grid: bx 0..63 -> BN=224 tiles; bx 64..511 -> BN=192 tiles.
__global__ __launch_bounds__(512, 2) void conv_gemm_kernel(
    const unsigned short* __restrict__ xm,
    const unsigned short* __restrict__ wB,
    float* __restrict__ out) {
    __shared__ __align__(1024) char lds[98304];   // 3 x (A 16KB + B 16KB)
    const int bx = blockIdx.x;
    if (bx < 64) {
        conv_body<7>(xm, wB, out, lds, bx * 224);
    } else {
        conv_body<6>(xm, wB, out, lds, 14336 + (bx - 64) * 192);
    }
}

// ---------------------------------------------------------------------------
extern "C" void kernel_launch(void* const* d_in, const int* in_sizes, int n_in,
                              void* d_out, int out_size, void* d_ws, size_t ws_size,
                              hipStream_t stream) {
    const float* x      = (const float*)d_in[0];
    const float* alpha  = (const float*)d_in[1];
    const float* weight = (const float*)d_in[2];
    float* out = (float*)d_out;

    unsigned short* xm = (unsigned short*)d_ws;
    unsigned short* wB = (unsigned short*)((char*)d_ws + XM_BYTES);

    modulate_kernel<<<dim3(NB * NT * HP), dim3(256), 0, stream>>>(x, alpha, xm);
    repack_w_kernel<<<dim3(9 * 256), dim3(256), 0, stream>>>(weight, wB);
    conv_gemm_kernel<<<dim3(512), dim3(512), 0, stream>>>(xm, wB, out);
}

// Round 16
// 156.519 us; speedup vs baseline: 1.1379x; 1.0018x over previous
//
#include <hip/hip_runtime.h>
#include <hip/hip_bf16.h>
#include <cstdint>

// Problem constants
#define CIN   256
#define COUT  256
#define NB    8
#define NT    16
#define NH    28
#define NW    28
#define HP    30
#define WP    30

#define XM_ELEMS   ((size_t)NB * NT * HP * WP * CIN)   // 29,491,200 bf16
#define XM_BYTES   (XM_ELEMS * 2)

typedef __bf16 bf16x8 __attribute__((ext_vector_type(8)));
typedef float  f32x4  __attribute__((ext_vector_type(4)));

#define AS1 __attribute__((address_space(1)))
#define AS3 __attribute__((address_space(3)))

static __device__ __forceinline__ unsigned short f2bf(float f) {
    __hip_bfloat16 h = __float2bfloat16(f);
    return __builtin_bit_cast(unsigned short, h);
}

// ---------------------------------------------------------------------------
// Pass 1: xm[b][t][hp][wp][ci] = bf16(x[b][ci][t][h][w] * alpha[b][ci][t])
// ---------------------------------------------------------------------------
__global__ void modulate_kernel(const float* __restrict__ x,
                                const float* __restrict__ alpha,
                                unsigned short* __restrict__ xm) {
    const int ci = threadIdx.x;
    const int blk = blockIdx.x;
    const int hp = blk % 30;
    const int bt = blk / 30;
    unsigned short* row = xm + (size_t)(bt * 900 + hp * 30) * 256;
    if (hp == 0 || hp == 29) {
        #pragma unroll
        for (int wp = 0; wp < 30; ++wp) row[wp * 256 + ci] = 0;
        return;
    }
    const int t = bt & 15, b = bt >> 4;
    const int h = hp - 1;
    const float a = alpha[(b * CIN + ci) * NT + t];
    const float* xrow = x + ((size_t)((b * CIN + ci) * NT + t) * NH + h) * NW;
    row[ci] = 0;
    row[29 * 256 + ci] = 0;
    const float4* xv = (const float4*)xrow;
    #pragma unroll
    for (int q = 0; q < 7; ++q) {
        float4 v = xv[q];
        row[(q * 4 + 1) * 256 + ci] = f2bf(v.x * a);
        row[(q * 4 + 2) * 256 + ci] = f2bf(v.y * a);
        row[(q * 4 + 3) * 256 + ci] = f2bf(v.z * a);
        row[(q * 4 + 4) * 256 + ci] = f2bf(v.w * a);
    }
}

// ---------------------------------------------------------------------------
// Pass 2: wB[tap][co][ci] = bf16(weight[co][ci][tap])
// ---------------------------------------------------------------------------
__global__ void repack_w_kernel(const float* __restrict__ w,
                                unsigned short* __restrict__ wB) {
    const int ci = threadIdx.x;
    const int tap = blockIdx.x >> 8;
    const int co  = blockIdx.x & 255;
    wB[((tap * 256 + co) * 256) + ci] = f2bf(w[(co * 256 + ci) * 9 + tap]);
}

// ---------------------------------------------------------------------------
// Pass 3: R15 EXACTLY, minus s_setprio (T5 is negative on lockstep GEMM,
// m190; suspected cause of port/MFMA alternation: prio-1 MFMA waves starve
// the sibling wave's prio-0 ds_read/stage issue -> LDS port runs after the
// MFMA period instead of under it). Everything else identical: mixed-BN
// grid (64 x BN224 + 448 x BN192 = N exactly; makespan-optimal for this
// geometry), 3-deep LDS staging, counted VMW(4) (never 0 in main loop),
// tap-inner K (L2-hot), 64B rows with slot^=(row>>1)&3 swizzle
// (0-conflict verified), pre-swizzled global_load_lds source.
// ---------------------------------------------------------------------------

#define BAR()    __builtin_amdgcn_s_barrier()
#define LGKM0()  asm volatile("s_waitcnt lgkmcnt(0)" ::: "memory")
#define VMW(N)   asm volatile("s_waitcnt vmcnt(" #N ")" ::: "memory")
#define SCHED0() __builtin_amdgcn_sched_barrier(0)

// stage K-tile (tapS,cicS) into buf P (0..2): A 256x32 (2 loads/wave),
// B 256(BN+dup)x32 (2 loads/wave). Advances tapS/cicS.
#define STAGE_F(P) do {                                                       \
    const int kh2 = (tapS * 11) >> 5;                                         \
    const int kw2 = tapS - 3 * kh2;                                           \
    const int aOff = tapS * 65536 + cicS * 32;                                \
    const int bOff = ((kh2 - 1) * 30 + (kw2 - 1)) * 256 + cicS * 32;          \
    _Pragma("unroll") for (int c_ = 0; c_ < 2; ++c_)                          \
        __builtin_amdgcn_global_load_lds(                                     \
            (const AS1 void*)(aSrc + aOff + c_ * 32768),                      \
            (AS3 void*)(lds + (P)*32768 + (c_*128 + wave*16)*64 + lane*16),   \
            16, 0, 0);                                                        \
    _Pragma("unroll") for (int c_ = 0; c_ < 2; ++c_)                          \
        __builtin_amdgcn_global_load_lds(                                     \
            (const AS1 void*)(bL[c_] + bOff),                                 \
            (AS3 void*)(lds + (P)*32768 + 16384 + (c_*128 + wave*16)*64 + lane*16), \
            16, 0, 0);                                                        \
    if (++tapS == 9) { tapS = 0; ++cicS; }                                    \
} while (0)

#define READF(S, P) do {                                                      \
    _Pragma("unroll") for (int m_ = 0; m_ < 4; ++m_)                          \
        fa##S[m_] = *(const bf16x8*)(lds + (P)*32768 +                        \
            (wm*64 + m_*16 + l15)*64 + readSwz);                              \
    _Pragma("unroll") for (int f_ = 0; f_ < NF; ++f_)                         \
        fb##S[f_] = *(const bf16x8*)(lds + (P)*32768 + 16384 +                \
            (wn*(NF*16) + f_*16 + l15)*64 + readSwz);                         \
} while (0)

#define MFMA_T(S) do {                                                        \
    _Pragma("unroll") for (int m_ = 0; m_ < 4; ++m_)                          \
    _Pragma("unroll") for (int f_ = 0; f_ < NF; ++f_)                         \
        acc[m_][f_] = __builtin_amdgcn_mfma_f32_16x16x32_bf16(                \
            fb##S[f_], fa##S[m_], acc[m_][f_], 0, 0, 0);                      \
} while (0)

// body j: compute CS=frags(j); read frags(j+1)->NS from NBUF=(j+1)%3;
// stage S(j+3) -> SBUF=j%3. VMW(4) drains S(j+1) (issued 2 bodies ago).
#define BODY_S(CS, NS, NBUF, SBUF) do {                                       \
    VMW(4);                                                                   \
    SCHED0();                                                                 \
    BAR();                                                                    \
    READF(NS, NBUF);                                                          \
    STAGE_F(SBUF);                                                            \
    SCHED0();                                                                 \
    MFMA_T(CS);                                                               \
    LGKM0();                                                                  \
    SCHED0();                                                                 \
} while (0)

// tail body (no stage); VMN = counted vmcnt target
#define BODY_N(CS, NS, NBUF, VMN) do {                                        \
    VMW(VMN);                                                                 \
    SCHED0();                                                                 \
    BAR();                                                                    \
    READF(NS, NBUF);                                                          \
    SCHED0();                                                                 \
    MFMA_T(CS);                                                               \
    LGKM0();                                                                  \
    SCHED0();                                                                 \
} while (0)

template<int NF>
__device__ __forceinline__ void conv_body(
    const unsigned short* __restrict__ xm,
    const unsigned short* __restrict__ wB,
    float* __restrict__ out,
    char* lds, const int n0)
{
    const int tid  = threadIdx.x;
    const int wave = tid >> 6;             // 0..7
    const int lane = tid & 63;
    const int l15  = lane & 15;
    const int wm   = wave >> 1;            // 0..3 co quarter (64)
    const int wn   = wave & 1;             // 0..1 n half (NF*16)
    const int BN   = NF * 32;              // 224 or 192

    // ---- staging sources (pre-swizzled ci slot; inverse of read swizzle) ----
    const int swzE = 8 * ((lane & 3) ^ ((lane >> 3) & 3));
    const unsigned short* aSrc = wB + (wave * 16 + (lane >> 2)) * 256 + swzE;

    const unsigned short* bL[2];
    #pragma unroll
    for (int c_ = 0; c_ < 2; ++c_) {
        int nl = c_ * 128 + wave * 16 + (lane >> 2);   // 0..255
        nl = nl > BN - 1 ? BN - 1 : nl;                // pad rows duplicate
        const int n  = n0 + nl;
        const int w_ = n % 28, h_ = (n / 28) % 28, bt = n / 784;
        bL[c_] = xm + (size_t)((bt * 30 + h_ + 1) * 30 + (w_ + 1)) * 256 + swzE;
    }

    // ---- fragment read base (slot swizzle (row>>1)&3, verified) ----
    const int readSwz = ((lane >> 4) ^ ((l15 >> 1) & 3)) << 4;

    f32x4 acc[4][NF];
    #pragma unroll
    for (int i = 0; i < 4; ++i)
        #pragma unroll
        for (int j = 0; j < NF; ++j) acc[i][j] = f32x4{0.f, 0.f, 0.f, 0.f};

    bf16x8 faA[4], fbA[NF], faB[4], fbB[NF];

    int tapS = 0, cicS = 0;
    // ---- prologue: S(0)->b0, S(1)->b1, S(2)->b2; frags(0) -> set A ----
    STAGE_F(0);
    STAGE_F(1);
    STAGE_F(2);
    VMW(8);                        // my S(0) landed (S(1),S(2) in flight)
    SCHED0();
    BAR();                         // all waves' S(0) landed
    READF(A, 0);                   // frags(0)
    LGKM0();
    SCHED0();

    // main: bodies j=0..65, pattern period 6 (buf%3 x set%2)
    #pragma unroll 1
    for (int it = 0; it < 11; ++it) {
        BODY_S(A, B, 1, 0);        // j=6it+0
        BODY_S(B, A, 2, 1);        // j=6it+1
        BODY_S(A, B, 0, 2);        // j=6it+2
        BODY_S(B, A, 1, 0);        // j=6it+3
        BODY_S(A, B, 2, 1);        // j=6it+4
        BODY_S(B, A, 0, 2);        // j=6it+5
    }
    // tail: j=66..70 (stages S(69..71) at j=66..68), then peel j=71
    BODY_S(A, B, 1, 0);            // j=66: stage S(69)
    BODY_S(B, A, 2, 1);            // j=67: stage S(70)
    BODY_S(A, B, 0, 2);            // j=68: stage S(71)
    BODY_N(B, A, 1, 4);            // j=69: drain S(70)
    BODY_N(A, B, 2, 0);            // j=70: drain S(71), read frags(71)
    MFMA_T(B);                     // j=71

    // ---- C-write: lane holds 4 consecutive n (rows) at one co (col) ----
    #pragma unroll
    for (int f = 0; f < NF; ++f) {
        const int n  = n0 + wn * (NF * 16) + f * 16 + ((lane >> 4) << 2);
        const int bt = n / 784;
        const int hw = n - bt * 784;
        const int b = bt >> 4, t = bt & 15;
        float* obase = out + ((size_t)(b * 256) * 16 + t) * 784 + hw;
        #pragma unroll
        for (int m = 0; m < 4; ++m) {
            const int co = wm * 64 + m * 16 + l15;
            *(f32x4*)(obase + (size_t)co * 12544) = acc[m][f];
        }
    }
}

// Mixed grid: bx 0..63 -> BN=224 tiles; bx 64..511 -> BN=192 tiles.
__global__ __launch_bounds__(512, 2) void conv_gemm_kernel(
    const unsigned short* __restrict__ xm,
    const unsigned short* __restrict__ wB,
    float* __restrict__ out) {
    __shared__ __align__(1024) char lds[98304];   // 3 x (A 16KB + B 16KB)
    const int bx = blockIdx.x;
    if (bx < 64) {
        conv_body<7>(xm, wB, out, lds, bx * 224);
    } else {
        conv_body<6>(xm, wB, out, lds, 14336 + (bx - 64) * 192);
    }
}

// ---------------------------------------------------------------------------
extern "C" void kernel_launch(void* const* d_in, const int* in_sizes, int n_in,
                              void* d_out, int out_size, void* d_ws, size_t ws_size,
                              hipStream_t stream) {
    const float* x      = (const float*)d_in[0];
    const float* alpha  = (const float*)d_in[1];
    const float* weight = (const float*)d_in[2];
    float* out = (float*)d_out;

    unsigned short* xm = (unsigned short*)d_ws;
    unsigned short* wB = (unsigned short*)((char*)d_ws + XM_BYTES);

    modulate_kernel<<<dim3(NB * NT * HP), dim3(256), 0, stream>>>(x, alpha, xm);
    repack_w_kernel<<<dim3(9 * 256), dim3(256), 0, stream>>>(weight, wB);
    conv_gemm_kernel<<<dim3(512), dim3(512), 0, stream>>>(xm, wB, out);
}